// Round 8
// baseline (85.097 us; speedup 1.0000x reference)
//
#include <hip/hip_runtime.h>
#include <hip/hip_fp16.h>

// GCN layer: out[N,16] = segment_sum(vals[e] * embeds[col[e], :], row[e])
// Round 8: node-centric scheme wasted ~2x work (per-node batch padding +
// max-over-groups trip divergence). Edge-centric now: each 4-lane group owns
// EXACTLY 16 contiguous edges (block = 1024 edges, perfectly balanced, no
// row_ptr). Sorted row -> run detection in-loop, flush via 4x
// global_atomic_add_f32 per lane at run boundaries + group-window end.
// fp16 table (L2-resident) kept. LDS staged metadata with pad-swizzle
// (all broadcast reads <=2-way bank conflicts = free).

#define D 16
constexpr int BLOCK = 256;
constexpr int WIN = 1024;   // edges per block (64 groups x 16)
constexpr int EPG = 16;     // edges per 4-lane group

typedef float f32x4 __attribute__((ext_vector_type(4)));
typedef int   i32x4 __attribute__((ext_vector_type(4)));
typedef unsigned int u32x2 __attribute__((ext_vector_type(2)));
typedef unsigned int u32x4 __attribute__((ext_vector_type(4)));

// Pad-swizzles: +4 u32 every 64 (cv) / 32 (row) u32 -> read stride across
// groups becomes 272B/144B -> bank spread, <=2-way conflicts.
__device__ __forceinline__ unsigned cvIdx(unsigned i) { return i + ((i >> 6) << 2); }
__device__ __forceinline__ unsigned rIdx(unsigned i)  { return i + ((i >> 5) << 2); }

__device__ __forceinline__ float2 h2f(unsigned u) {
  union { unsigned u; __half2 h; } c; c.u = u;
  return __half22float2(c.h);
}

// Prep: repack embeds f32 -> fp16 table (3.2MB, L2-resident). 8 halves/thread.
__global__ __launch_bounds__(BLOCK) void repack_kernel(
    const float* __restrict__ embeds, int N, __half* __restrict__ table) {
  const long long t = (long long)blockIdx.x * BLOCK + threadIdx.x;
  if (t < (long long)N * 2) {
    const f32x4* src = (const f32x4*)embeds + t * 2;
    f32x4 a = src[0];
    f32x4 b = src[1];
    union { __half2 h[4]; u32x4 u; } o;
    o.h[0] = __floats2half2_rn(a[0], a[1]);
    o.h[1] = __floats2half2_rn(a[2], a[3]);
    o.h[2] = __floats2half2_rn(b[0], b[1]);
    o.h[3] = __floats2half2_rn(b[2], b[3]);
    *((u32x4*)table + t) = o.u;
  }
}

// One 8-edge batch: read staged meta (broadcast ds_reads), 8 independent
// gathers, consume with run-boundary flushes. Fully unrolled -> static
// register indexing (no scratch).
template <bool HALF>
__device__ __forceinline__ void do8(const unsigned* s_cv, const unsigned* s_row,
                                    unsigned i0, unsigned rn_last, f32x4& acc,
                                    const char* tb, unsigned q,
                                    float* __restrict__ out) {
  const unsigned ci = cvIdx(i0 * 2);
  const unsigned ri = rIdx(i0);
  u32x4 m0 = *(const u32x4*)(s_cv + ci);
  u32x4 m1 = *(const u32x4*)(s_cv + ci + 4);
  u32x4 m2 = *(const u32x4*)(s_cv + ci + 8);
  u32x4 m3 = *(const u32x4*)(s_cv + ci + 12);
  u32x4 r0 = *(const u32x4*)(s_row + ri);
  u32x4 r1 = *(const u32x4*)(s_row + ri + 4);
  const unsigned cc[8] = {m0[0], m0[2], m1[0], m1[2], m2[0], m2[2], m3[0], m3[2]};
  const unsigned vv[8] = {m0[1], m0[3], m1[1], m1[3], m2[1], m2[3], m3[1], m3[3]};
  const unsigned rr[9] = {r0[0], r0[1], r0[2], r0[3],
                          r1[0], r1[1], r1[2], r1[3], rn_last};
  if constexpr (HALF) {
    u32x2 G[8];
    #pragma unroll
    for (int i = 0; i < 8; ++i)
      G[i] = *(const u32x2*)(tb + (size_t)(cc[i] << 5) + (q << 3));
    #pragma unroll
    for (int i = 0; i < 8; ++i) {
      const float w = __uint_as_float(vv[i]);
      const float2 lo = h2f(G[i][0]), hi = h2f(G[i][1]);
      acc[0] = fmaf(w, lo.x, acc[0]);
      acc[1] = fmaf(w, lo.y, acc[1]);
      acc[2] = fmaf(w, hi.x, acc[2]);
      acc[3] = fmaf(w, hi.y, acc[3]);
      if (rr[i] != rr[i + 1]) {
        float* p = out + ((size_t)rr[i] << 4) + (q << 2);
        atomicAdd(p + 0, acc[0]);
        atomicAdd(p + 1, acc[1]);
        atomicAdd(p + 2, acc[2]);
        atomicAdd(p + 3, acc[3]);
        acc = (f32x4){0.f, 0.f, 0.f, 0.f};
      }
    }
  } else {
    f32x4 X[8];
    #pragma unroll
    for (int i = 0; i < 8; ++i)
      X[i] = *(const f32x4*)(tb + (size_t)(cc[i] << 6) + (q << 4));
    #pragma unroll
    for (int i = 0; i < 8; ++i) {
      const float w = __uint_as_float(vv[i]);
      acc[0] = fmaf(w, X[i][0], acc[0]);
      acc[1] = fmaf(w, X[i][1], acc[1]);
      acc[2] = fmaf(w, X[i][2], acc[2]);
      acc[3] = fmaf(w, X[i][3], acc[3]);
      if (rr[i] != rr[i + 1]) {
        float* p = out + ((size_t)rr[i] << 4) + (q << 2);
        atomicAdd(p + 0, acc[0]);
        atomicAdd(p + 1, acc[1]);
        atomicAdd(p + 2, acc[2]);
        atomicAdd(p + 3, acc[3]);
        acc = (f32x4){0.f, 0.f, 0.f, 0.f};
      }
    }
  }
}

template <bool HALF>
__global__ __launch_bounds__(BLOCK) void gcn_edge_kernel(
    const int* __restrict__ row, const int* __restrict__ col,
    const float* __restrict__ vals, const void* __restrict__ tab,
    float* __restrict__ out, int E) {
  __shared__ __align__(16) unsigned s_cv[2176];   // 1024 x {col,valbits} + pads
  __shared__ __align__(16) unsigned s_row[1152];  // 1024 rows + pads

  const int t = threadIdx.x;
  const long long W0 = (long long)blockIdx.x * WIN;

  {  // Stage 4 edges per thread (coalesced 16B loads; tail zero-padded).
    const long long e = W0 + t * 4;
    unsigned c[4], v[4], r[4];
    if (e + 3 < E) {
      i32x4 c4 = *(const i32x4*)(col + e);
      f32x4 v4 = *(const f32x4*)(vals + e);
      i32x4 r4 = *(const i32x4*)(row + e);
      #pragma unroll
      for (int k = 0; k < 4; ++k) {
        c[k] = (unsigned)c4[k];
        v[k] = __float_as_uint(v4[k]);
        r[k] = (unsigned)r4[k];
      }
    } else {
      #pragma unroll
      for (int k = 0; k < 4; ++k) {
        const bool ok = (e + k < E);
        c[k] = ok ? (unsigned)col[e + k] : 0u;
        v[k] = ok ? __float_as_uint(vals[e + k]) : 0u;  // w=0: no contribution
        r[k] = ok ? (unsigned)row[e + k] : 0u;          // flush target 0 gets +0
      }
    }
    *(u32x4*)(s_cv + cvIdx(t * 8))     = (u32x4){c[0], v[0], c[1], v[1]};
    *(u32x4*)(s_cv + cvIdx(t * 8) + 4) = (u32x4){c[2], v[2], c[3], v[3]};
    *(u32x4*)(s_row + rIdx(t * 4))     = (u32x4){r[0], r[1], r[2], r[3]};
  }
  __syncthreads();

  const int g = t >> 2;
  const unsigned q = (unsigned)(t & 3);
  const char* tb = (const char*)tab;
  const unsigned base = (unsigned)g * EPG;

  f32x4 acc = {0.f, 0.f, 0.f, 0.f};
  const unsigned rn8 = s_row[rIdx(base + 8)];  // row of edge base+8 (lookahead)
  do8<HALF>(s_cv, s_row, base,     rn8,         acc, tb, q, out);
  do8<HALF>(s_cv, s_row, base + 8, 0xFFFFFFFFu, acc, tb, q, out);  // forced flush
}

extern "C" void kernel_launch(void* const* d_in, const int* in_sizes, int n_in,
                              void* d_out, int out_size, void* d_ws, size_t ws_size,
                              hipStream_t stream) {
  const int*   row    = (const int*)d_in[0];
  const int*   col    = (const int*)d_in[1];
  const float* vals   = (const float*)d_in[2];
  const float* embeds = (const float*)d_in[3];

  const int E = in_sizes[0];
  const int N = in_sizes[3] / D;

  const size_t tbl_bytes = (size_t)N * D * sizeof(__half);
  const bool use_half = (ws_size >= tbl_bytes);
  __half* table = (__half*)d_ws;

  // Atomic accumulation -> zero the output every call (graph-capture safe).
  hipMemsetAsync(d_out, 0, (size_t)out_size * sizeof(float), stream);

  if (use_half) {
    const int gridP = (int)(((long long)N * 2 + BLOCK - 1) / BLOCK);
    repack_kernel<<<gridP, BLOCK, 0, stream>>>(embeds, N, table);
  }

  const int grid = (int)(((long long)E + WIN - 1) / WIN);
  if (use_half) {
    gcn_edge_kernel<true><<<grid, BLOCK, 0, stream>>>(
        row, col, vals, table, (float*)d_out, E);
  } else {
    gcn_edge_kernel<false><<<grid, BLOCK, 0, stream>>>(
        row, col, vals, embeds, (float*)d_out, E);
  }
}

// Round 9
// 51.602 us; speedup vs baseline: 1.6491x; 1.6491x over previous
//
#include <hip/hip_runtime.h>
#include <hip/hip_fp16.h>

// GCN layer: out[N,16] = segment_sum(vals[e] * embeds[col[e], :], row[e])
// Round 9 = r6 (LDS metadata staging, 8 gathers in flight, no global atomics)
// + r8's perfect edge balance (each 4-lane group owns exactly 16 edges/stage)
// + NEW: block-local LDS output tile. A block owns nodes [n0,n0+64); all its
// window edges scatter into s_out[64][16] via cheap LDS atomics at run
// boundaries; one coalesced global store pass at the end. No memset needed.

#define D 16
constexpr int BLOCK = 256;
constexpr int NPB = 64;        // nodes per block
constexpr int SMEM_E = 1024;   // edges staged per stage

typedef float f32x4 __attribute__((ext_vector_type(4)));
typedef int   i32x4 __attribute__((ext_vector_type(4)));
typedef unsigned int u32x2 __attribute__((ext_vector_type(2)));
typedef unsigned int u32x4 __attribute__((ext_vector_type(4)));

// Pad-swizzles (+4 u32 per 64/32) keep cross-group ds_read_b128 <=2-way.
__device__ __forceinline__ unsigned cvIdx(unsigned i) { return i + ((i >> 6) << 2); }
__device__ __forceinline__ unsigned rIdx(unsigned i)  { return i + ((i >> 5) << 2); }

__device__ __forceinline__ float2 h2f(unsigned u) {
  union { unsigned u; __half2 h; } c; c.u = u;
  return __half22float2(c.h);
}

// Fused prep: repack embeds f32->f16 (task A) + row_ptr adjacent-diff (task B).
__global__ __launch_bounds__(BLOCK) void prep_kernel(
    const int* __restrict__ row, int E,
    const float* __restrict__ embeds, int N,
    int* __restrict__ row_ptr, __half* __restrict__ table) {
  const long long t = (long long)blockIdx.x * BLOCK + threadIdx.x;

  if (table != nullptr) {
    if (t < (long long)N * 2) {   // 8 halves per thread
      const f32x4* src = (const f32x4*)embeds + t * 2;
      f32x4 a = src[0];
      f32x4 b = src[1];
      union { __half2 h[4]; u32x4 u; } o;
      o.h[0] = __floats2half2_rn(a[0], a[1]);
      o.h[1] = __floats2half2_rn(a[2], a[3]);
      o.h[2] = __floats2half2_rn(b[0], b[1]);
      o.h[3] = __floats2half2_rn(b[2], b[3]);
      *((u32x4*)table + t) = o.u;
    }
  }

  const long long e = t * 4;
  if (e < E) {
    int prev = (e == 0) ? -1 : row[e - 1];
    const int cnt = (E - e >= 4) ? 4 : (int)(E - e);
    int r[4];
    if (cnt == 4) {
      i32x4 r4 = *(const i32x4*)(row + e);
      r[0] = r4[0]; r[1] = r4[1]; r[2] = r4[2]; r[3] = r4[3];
    } else {
      for (int k = 0; k < cnt; ++k) r[k] = row[e + k];
    }
    for (int k = 0; k < cnt; ++k) {
      for (int n = prev + 1; n <= r[k]; ++n) row_ptr[n] = (int)e + k;
      prev = r[k];
    }
    if (e + cnt == E) {
      for (int n = prev + 1; n <= N; ++n) row_ptr[n] = E;
    }
  }
}

// 8-edge sub-batch: 6 broadcast ds_read_b128 of metadata, 8 independent
// gathers, fma-consume, flush partial sums into LDS tile at run boundaries.
template <bool HALF>
__device__ __forceinline__ void do8(const unsigned* s_cv, const unsigned* s_row,
                                    unsigned i0, unsigned rn_last, f32x4& acc,
                                    const char* tb, unsigned q,
                                    float* __restrict__ s_out) {
  const unsigned ci = cvIdx(i0 * 2);
  u32x4 m0 = *(const u32x4*)(s_cv + ci);
  u32x4 m1 = *(const u32x4*)(s_cv + ci + 4);
  u32x4 m2 = *(const u32x4*)(s_cv + ci + 8);
  u32x4 m3 = *(const u32x4*)(s_cv + ci + 12);
  u32x4 r0 = *(const u32x4*)(s_row + rIdx(i0));
  u32x4 r1 = *(const u32x4*)(s_row + rIdx(i0 + 4));
  const unsigned cc[8] = {m0[0], m0[2], m1[0], m1[2], m2[0], m2[2], m3[0], m3[2]};
  const unsigned vv[8] = {m0[1], m0[3], m1[1], m1[3], m2[1], m2[3], m3[1], m3[3]};
  const unsigned rr[9] = {r0[0], r0[1], r0[2], r0[3],
                          r1[0], r1[1], r1[2], r1[3], rn_last};
  if constexpr (HALF) {
    u32x2 G[8];
    #pragma unroll
    for (int i = 0; i < 8; ++i)
      G[i] = *(const u32x2*)(tb + (size_t)(cc[i] << 5) + (q << 3));
    #pragma unroll
    for (int i = 0; i < 8; ++i) {
      const float w = __uint_as_float(vv[i]);
      const float2 lo = h2f(G[i][0]), hi = h2f(G[i][1]);
      acc[0] = fmaf(w, lo.x, acc[0]);
      acc[1] = fmaf(w, lo.y, acc[1]);
      acc[2] = fmaf(w, hi.x, acc[2]);
      acc[3] = fmaf(w, hi.y, acc[3]);
      if (rr[i] != rr[i + 1]) {   // uniform across the 4-lane group
        float* p = s_out + rr[i] * D + q * 4;
        atomicAdd(p + 0, acc[0]);
        atomicAdd(p + 1, acc[1]);
        atomicAdd(p + 2, acc[2]);
        atomicAdd(p + 3, acc[3]);
        acc = (f32x4){0.f, 0.f, 0.f, 0.f};
      }
    }
  } else {
    f32x4 X[8];
    #pragma unroll
    for (int i = 0; i < 8; ++i)
      X[i] = *(const f32x4*)(tb + (size_t)(cc[i] << 6) + (q << 4));
    #pragma unroll
    for (int i = 0; i < 8; ++i) {
      const float w = __uint_as_float(vv[i]);
      acc[0] = fmaf(w, X[i][0], acc[0]);
      acc[1] = fmaf(w, X[i][1], acc[1]);
      acc[2] = fmaf(w, X[i][2], acc[2]);
      acc[3] = fmaf(w, X[i][3], acc[3]);
      if (rr[i] != rr[i + 1]) {
        float* p = s_out + rr[i] * D + q * 4;
        atomicAdd(p + 0, acc[0]);
        atomicAdd(p + 1, acc[1]);
        atomicAdd(p + 2, acc[2]);
        atomicAdd(p + 3, acc[3]);
        acc = (f32x4){0.f, 0.f, 0.f, 0.f};
      }
    }
  }
}

template <bool HALF>
__global__ __launch_bounds__(BLOCK) void gcn_win_kernel(
    const int* __restrict__ row, const int* __restrict__ col,
    const float* __restrict__ vals, const void* __restrict__ tab,
    const int* __restrict__ row_ptr, f32x4* __restrict__ out4, int N, int E) {
  __shared__ __align__(16) unsigned s_cv[2176];   // 1024x{col,val} + pads
  __shared__ __align__(16) unsigned s_row[1160];  // 1024 tile-rows + pads + sentinel
  __shared__ __align__(16) float    s_out[NPB * D];  // 64x16 output tile

  const int t = threadIdx.x;
  const int n0 = blockIdx.x * NPB;
  const int nEnd = (n0 + NPB < N) ? n0 + NPB : N;

  *(f32x4*)(s_out + t * 4) = (f32x4){0.f, 0.f, 0.f, 0.f};

  const int realWb = row_ptr[n0];
  const int Wb = realWb & ~3;           // aligned staging base
  const int We = row_ptr[nEnd];

  const int g = t >> 2;
  const unsigned q = (unsigned)(t & 3);
  const char* tb = (const char*)tab;

  for (int W0 = Wb; W0 < We; W0 += SMEM_E) {
    const int cnt  = (SMEM_E < We - W0) ? SMEM_E : (We - W0);
    const int cntP = (cnt + 15) & ~15;
    __syncthreads();   // s_out zero-init visible / s_* reuse across stages

    {  // Stage 4 edges per thread (one pass: 256*4 = 1024).
      const int i = t * 4;
      if (i < cntP) {
        const int e = W0 + i;
        unsigned c[4], v[4], r[4];
        if (e + 3 < E) {
          i32x4 c4 = *(const i32x4*)(col + e);
          f32x4 v4 = *(const f32x4*)(vals + e);
          i32x4 r4 = *(const i32x4*)(row + e);
          #pragma unroll
          for (int k = 0; k < 4; ++k) {
            const bool ok = (e + k >= realWb) && (e + k < We);
            c[k] = ok ? (unsigned)c4[k] : 0u;
            v[k] = ok ? __float_as_uint(v4[k]) : 0u;
            r[k] = ok ? (unsigned)(r4[k] - n0) : 0u;
          }
        } else {
          #pragma unroll
          for (int k = 0; k < 4; ++k) {
            const bool ok = (e + k >= realWb) && (e + k < We);
            c[k] = ok ? (unsigned)col[e + k] : 0u;
            v[k] = ok ? __float_as_uint(vals[e + k]) : 0u;
            r[k] = ok ? (unsigned)(row[e + k] - n0) : 0u;
          }
        }
        *(u32x4*)(s_cv + cvIdx((unsigned)i * 2))     = (u32x4){c[0], v[0], c[1], v[1]};
        *(u32x4*)(s_cv + cvIdx((unsigned)i * 2) + 4) = (u32x4){c[2], v[2], c[3], v[3]};
        *(u32x4*)(s_row + rIdx((unsigned)i))         = (u32x4){r[0], r[1], r[2], r[3]};
      }
      if (t == 0) s_row[rIdx((unsigned)cntP)] = 0xFFFFFFFFu;  // stage-end sentinel
    }
    __syncthreads();

    const unsigned base = (unsigned)g * 16;   // this group's exact 16 edges
    if ((int)base < cntP) {
      f32x4 acc = {0.f, 0.f, 0.f, 0.f};
      const unsigned rn8  = s_row[rIdx(base + 8)];
      const unsigned rn16 = s_row[rIdx(base + 16)];  // next slice or sentinel
      do8<HALF>(s_cv, s_row, base,     rn8,  acc, tb, q, s_out);
      do8<HALF>(s_cv, s_row, base + 8, rn16, acc, tb, q, s_out);
      // Forced flush: run may continue into next group's slice (acc may be 0).
      const unsigned lr = s_row[rIdx(base + 15)];
      float* p = s_out + lr * D + q * 4;
      atomicAdd(p + 0, acc[0]);
      atomicAdd(p + 1, acc[1]);
      atomicAdd(p + 2, acc[2]);
      atomicAdd(p + 3, acc[3]);
    }
  }

  __syncthreads();
  const int node = n0 + (t >> 2);
  if (node < nEnd) {
    f32x4 o = *(const f32x4*)(s_out + (t >> 2) * D + (t & 3) * 4);
    __builtin_nontemporal_store(o, out4 + (size_t)node * 4 + (t & 3));
  }
}

extern "C" void kernel_launch(void* const* d_in, const int* in_sizes, int n_in,
                              void* d_out, int out_size, void* d_ws, size_t ws_size,
                              hipStream_t stream) {
  const int*   row    = (const int*)d_in[0];
  const int*   col    = (const int*)d_in[1];
  const float* vals   = (const float*)d_in[2];
  const float* embeds = (const float*)d_in[3];

  const int E = in_sizes[0];
  const int N = in_sizes[3] / D;

  const size_t rp_bytes  = ((size_t)(N + 1) * 4 + 511) & ~(size_t)511;
  const size_t tbl_bytes = (size_t)N * D * sizeof(__half);
  const bool use_half = (ws_size >= rp_bytes + tbl_bytes) && (E >= 4);

  int*    row_ptr = (int*)d_ws;
  __half* table   = use_half ? (__half*)((char*)d_ws + rp_bytes) : nullptr;

  {
    long long chunksB = ((long long)E + 3) / 4;
    long long chunksA = use_half ? (long long)N * 2 : 0;
    long long threads = chunksB > chunksA ? chunksB : chunksA;
    int grid = (int)((threads + BLOCK - 1) / BLOCK);
    prep_kernel<<<grid, BLOCK, 0, stream>>>(row, E, embeds, N, row_ptr, table);
  }
  {
    const int grid = (N + NPB - 1) / NPB;
    if (use_half) {
      gcn_win_kernel<true><<<grid, BLOCK, 0, stream>>>(
          row, col, vals, table, row_ptr, (f32x4*)d_out, N, E);
    } else {
      gcn_win_kernel<false><<<grid, BLOCK, 0, stream>>>(
          row, col, vals, embeds, row_ptr, (f32x4*)d_out, N, E);
    }
  }
}

// Round 10
// 40.576 us; speedup vs baseline: 2.0973x; 1.2718x over previous
//
#include <hip/hip_runtime.h>
#include <hip/hip_fp16.h>

// GCN layer: out[N,16] = segment_sum(vals[e] * embeds[col[e], :], row[e])
// Round 10: r7's VGPR=36 proved the compiler sinks gathers to uses (MLP
// collapses to ~2-4 in flight) in every prior structure. This round: r6 base
// (node-centric, LDS-staged metadata, fp16 L2-resident table, plain stores)
// + sched_barrier(0)-fenced software pipeline: per 8-edge iter, ds_read
// meta(k+2), issue 8 gathers(k+1), FENCE, consume(k). 16 gathers in flight,
// compiler cannot reorder across the fence. Expect VGPR ~90-120 as proof.

#define D 16
constexpr int BLOCK = 256;
constexpr int NPB = 64;        // nodes per block (4 lanes/node)
constexpr int SMEM_E = 3072;   // staged edges per window

typedef float f32x4 __attribute__((ext_vector_type(4)));
typedef int   i32x4 __attribute__((ext_vector_type(4)));
typedef unsigned int u32x2 __attribute__((ext_vector_type(2)));
typedef unsigned int u32x4 __attribute__((ext_vector_type(4)));

// Pad-swizzle: +4 u32 per 64 logical u32 -> cross-group broadcast ds_reads
// land on distinct bank clusters (<=2-way, free). 16-u32 runs at 16-multiples
// never cross a pad boundary.
__device__ __forceinline__ unsigned cvIdx(unsigned i) { return i + ((i >> 6) << 2); }

__device__ __forceinline__ float2 h2f(unsigned u) {
  union { unsigned u; __half2 h; } c; c.u = u;
  return __half22float2(c.h);
}

// Fused prep: repack embeds f32->f16 (task A) + row_ptr adjacent-diff (task B).
__global__ __launch_bounds__(BLOCK) void prep_kernel(
    const int* __restrict__ row, int E,
    const float* __restrict__ embeds, int N,
    int* __restrict__ row_ptr, __half* __restrict__ table) {
  const long long t = (long long)blockIdx.x * BLOCK + threadIdx.x;

  if (table != nullptr) {
    if (t < (long long)N * 2) {   // 8 halves per thread
      const f32x4* src = (const f32x4*)embeds + t * 2;
      f32x4 a = src[0];
      f32x4 b = src[1];
      union { __half2 h[4]; u32x4 u; } o;
      o.h[0] = __floats2half2_rn(a[0], a[1]);
      o.h[1] = __floats2half2_rn(a[2], a[3]);
      o.h[2] = __floats2half2_rn(b[0], b[1]);
      o.h[3] = __floats2half2_rn(b[2], b[3]);
      *((u32x4*)table + t) = o.u;
    }
  }

  const long long e = t * 4;
  if (e < E) {
    int prev = (e == 0) ? -1 : row[e - 1];
    const int cnt = (E - e >= 4) ? 4 : (int)(E - e);
    int r[4];
    if (cnt == 4) {
      i32x4 r4 = *(const i32x4*)(row + e);
      r[0] = r4[0]; r[1] = r4[1]; r[2] = r4[2]; r[3] = r4[3];
    } else {
      for (int k = 0; k < cnt; ++k) r[k] = row[e + k];
    }
    for (int k = 0; k < cnt; ++k) {
      for (int n = prev + 1; n <= r[k]; ++n) row_ptr[n] = (int)e + k;
      prev = r[k];
    }
    if (e + cnt == E) {
      for (int n = prev + 1; n <= N; ++n) row_ptr[n] = E;
    }
  }
}

__device__ __forceinline__ void ldmeta(const unsigned* __restrict__ s_cv,
                                       unsigned i0, u32x4 M[4]) {
  const unsigned ci = cvIdx(i0 * 2);
  M[0] = *(const u32x4*)(s_cv + ci);
  M[1] = *(const u32x4*)(s_cv + ci + 4);
  M[2] = *(const u32x4*)(s_cv + ci + 8);
  M[3] = *(const u32x4*)(s_cv + ci + 12);
}

__device__ __forceinline__ void gath(const char* __restrict__ tb,
                                     const u32x4 M[4], unsigned q8, u32x2 G[8]) {
  G[0] = *(const u32x2*)(tb + (size_t)(M[0][0] << 5) + q8);
  G[1] = *(const u32x2*)(tb + (size_t)(M[0][2] << 5) + q8);
  G[2] = *(const u32x2*)(tb + (size_t)(M[1][0] << 5) + q8);
  G[3] = *(const u32x2*)(tb + (size_t)(M[1][2] << 5) + q8);
  G[4] = *(const u32x2*)(tb + (size_t)(M[2][0] << 5) + q8);
  G[5] = *(const u32x2*)(tb + (size_t)(M[2][2] << 5) + q8);
  G[6] = *(const u32x2*)(tb + (size_t)(M[3][0] << 5) + q8);
  G[7] = *(const u32x2*)(tb + (size_t)(M[3][2] << 5) + q8);
}

__device__ __forceinline__ void cons8(f32x4& acc, const u32x4 M[4],
                                      const u32x2 G[8], int e, int gb,
                                      unsigned span) {
  const unsigned vv[8] = {M[0][1], M[0][3], M[1][1], M[1][3],
                          M[2][1], M[2][3], M[3][1], M[3][3]};
  #pragma unroll
  for (int i = 0; i < 8; ++i) {
    const float w = ((unsigned)(e + i - gb) < span) ? __uint_as_float(vv[i]) : 0.f;
    const float2 lo = h2f(G[i][0]), hi = h2f(G[i][1]);
    acc[0] = fmaf(w, lo.x, acc[0]);
    acc[1] = fmaf(w, lo.y, acc[1]);
    acc[2] = fmaf(w, hi.x, acc[2]);
    acc[3] = fmaf(w, hi.y, acc[3]);
  }
}

__global__ __launch_bounds__(BLOCK) void gcn_half_kernel(
    const int* __restrict__ col, const float* __restrict__ vals,
    const __half* __restrict__ table, const int* __restrict__ row_ptr,
    f32x4* __restrict__ out4, int N, int E) {
  __shared__ __align__(16) unsigned s_cv[SMEM_E * 2 + (SMEM_E * 2 / 64) * 4];

  const int t = threadIdx.x;
  const int n0 = blockIdx.x * NPB;
  const int nEnd = (n0 + NPB < N) ? n0 + NPB : N;
  const int g = t >> 2;
  const unsigned q8 = (unsigned)((t & 3) << 3);
  const int node = n0 + g;
  const bool active = (node < nEnd);

  const int Wb = row_ptr[n0] & ~3;
  const int We = row_ptr[nEnd];
  const int beg = active ? row_ptr[node] : 0;
  const int end = active ? row_ptr[node + 1] : 0;
  const char* tb = (const char*)table;

  f32x4 acc = {0.f, 0.f, 0.f, 0.f};

  for (int W0 = Wb; W0 < We; W0 += SMEM_E) {
    const int cnt  = (SMEM_E < We - W0) ? SMEM_E : (We - W0);
    const int cntP = (cnt + 7) & ~7;
    __syncthreads();
    // Cooperative coalesced staging: 4 edges/thread/pass, 3 passes.
    for (int i = t * 4; i < cntP; i += BLOCK * 4) {
      const int e = W0 + i;
      unsigned c[4], v[4];
      if (e + 3 < E) {
        i32x4 c4 = *(const i32x4*)(col + e);
        f32x4 v4 = *(const f32x4*)(vals + e);
        #pragma unroll
        for (int k = 0; k < 4; ++k) {
          c[k] = (unsigned)c4[k];
          v[k] = __float_as_uint(v4[k]);
        }
      } else {
        #pragma unroll
        for (int k = 0; k < 4; ++k) {
          const bool ok = (e + k < E);
          c[k] = ok ? (unsigned)col[e + k] : 0u;
          v[k] = ok ? __float_as_uint(vals[e + k]) : 0u;
        }
      }
      *(u32x4*)(s_cv + cvIdx((unsigned)i * 2))     = (u32x4){c[0], v[0], c[1], v[1]};
      *(u32x4*)(s_cv + cvIdx((unsigned)i * 2) + 4) = (u32x4){c[2], v[2], c[3], v[3]};
    }
    __syncthreads();

    const int gb = (beg > W0) ? beg : W0;
    const int ge = (end < W0 + cnt) ? end : (W0 + cnt);
    if (ge > gb) {
      const unsigned span = (unsigned)(ge - gb);
      const int e0 = W0 + ((gb - W0) & ~7);
      const int e1 = e0 + ((ge - e0 + 7) & ~7);     // <= W0 + cntP
      const int eL = e1 - 8;                        // last batch start

      u32x4 M0[4], M1[4], M2[4];
      u32x2 G0[8], G1[8];
      const int p1 = (e0 + 8 < eL) ? e0 + 8 : eL;
      ldmeta(s_cv, (unsigned)(e0 - W0), M0);
      ldmeta(s_cv, (unsigned)(p1 - W0), M1);
      gath(tb, M0, q8, G0);

      for (int e = e0; e < e1; e += 8) {
        const int p2 = (e + 16 < eL) ? e + 16 : eL;
        ldmeta(s_cv, (unsigned)(p2 - W0), M2);   // meta for batch k+2
        gath(tb, M1, q8, G1);                    // gathers for batch k+1
        __builtin_amdgcn_sched_barrier(0);       // nothing crosses: 16 in flight
        cons8(acc, M0, G0, e, gb, span);         // consume batch k
        #pragma unroll
        for (int j = 0; j < 4; ++j) { M0[j] = M1[j]; M1[j] = M2[j]; }
        #pragma unroll
        for (int j = 0; j < 8; ++j) { G0[j] = G1[j]; }
      }
    }
  }

  if (active) {
    __builtin_nontemporal_store(acc, out4 + (size_t)node * 4 + (t & 3));
  }
}

// Fallback (f32 gathers straight from embeds) if ws can't hold the table.
__global__ __launch_bounds__(BLOCK) void gcn_node_f32_kernel(
    const int* __restrict__ col, const float* __restrict__ vals,
    const f32x4* __restrict__ embeds4, const int* __restrict__ row_ptr,
    f32x4* __restrict__ out4, int N, int E) {
  const int t = blockIdx.x * BLOCK + threadIdx.x;
  const int node = t >> 2;
  const int q = t & 3;
  if (node >= N) return;
  const int beg = row_ptr[node];
  const int end = row_ptr[node + 1];
  f32x4 acc = {0.f, 0.f, 0.f, 0.f};
  for (int e = beg; e < end; ++e) {
    acc += vals[e] * embeds4[(long long)col[e] * 4 + q];
  }
  __builtin_nontemporal_store(acc, out4 + (long long)node * 4 + q);
}

extern "C" void kernel_launch(void* const* d_in, const int* in_sizes, int n_in,
                              void* d_out, int out_size, void* d_ws, size_t ws_size,
                              hipStream_t stream) {
  const int*   row    = (const int*)d_in[0];
  const int*   col    = (const int*)d_in[1];
  const float* vals   = (const float*)d_in[2];
  const float* embeds = (const float*)d_in[3];

  const int E = in_sizes[0];
  const int N = in_sizes[3] / D;

  const size_t rp_bytes  = ((size_t)(N + 1) * 4 + 511) & ~(size_t)511;
  const size_t tbl_bytes = (size_t)N * D * sizeof(__half);
  const bool use_half = (ws_size >= rp_bytes + tbl_bytes) && (E >= 8);

  int*    row_ptr = (int*)d_ws;
  __half* table   = use_half ? (__half*)((char*)d_ws + rp_bytes) : nullptr;

  {
    long long chunksB = ((long long)E + 3) / 4;
    long long chunksA = use_half ? (long long)N * 2 : 0;
    long long threads = chunksB > chunksA ? chunksB : chunksA;
    int grid = (int)((threads + BLOCK - 1) / BLOCK);
    prep_kernel<<<grid, BLOCK, 0, stream>>>(row, E, embeds, N, row_ptr, table);
  }
  if (use_half) {
    const int grid = (N + NPB - 1) / NPB;
    gcn_half_kernel<<<grid, BLOCK, 0, stream>>>(
        col, vals, table, row_ptr, (f32x4*)d_out, N, E);
  } else {
    long long threads = (long long)N * 4;
    int grid = (int)((threads + BLOCK - 1) / BLOCK);
    gcn_node_f32_kernel<<<grid, BLOCK, 0, stream>>>(
        col, vals, (const f32x4*)embeds, row_ptr, (f32x4*)d_out, N, E);
  }
}

// Round 11
// 38.200 us; speedup vs baseline: 2.2277x; 1.0622x over previous
//
#include <hip/hip_runtime.h>
#include <hip/hip_fp16.h>

// GCN layer: out[N,16] = segment_sum(vals[e] * embeds[col[e], :], row[e])
// Round 11: evidence (r3==r4 fetch-invariance; r10 MLP-invariance) says the
// bound is gather ADDRESS-processing throughput (TA path), ~4 addr/edge in
// every prior variant. This round halves it: 2 lanes x dwordx4 per edge
// (lanes 0,1 = edge e's 16B halves, lanes 2,3 = edge e+1), 4 gather instrs
// per 8-edge batch. Lane accumulates 8 features of its edge-parity; one
// shfl_xor(2) pass combines at the end. Otherwise identical to r6 (best).

#define D 16
constexpr int BLOCK = 256;
constexpr int NPB = 64;        // nodes per block (4 lanes/node)
constexpr int SMEM_E = 3072;   // staged edges per window

typedef float f32x4 __attribute__((ext_vector_type(4)));
typedef int   i32x4 __attribute__((ext_vector_type(4)));
typedef unsigned int u32x4 __attribute__((ext_vector_type(4)));

// Pad-swizzle: +4 u32 per 64 logical u32 -> cross-group broadcast ds_reads
// spread across banks; 16-u32 batch runs at 16-multiples never cross a pad.
__device__ __forceinline__ unsigned cvIdx(unsigned i) { return i + ((i >> 6) << 2); }

__device__ __forceinline__ float2 h2f(unsigned u) {
  union { unsigned u; __half2 h; } c; c.u = u;
  return __half22float2(c.h);
}

// Fused prep: repack embeds f32->f16 (task A) + row_ptr adjacent-diff (task B).
__global__ __launch_bounds__(BLOCK) void prep_kernel(
    const int* __restrict__ row, int E,
    const float* __restrict__ embeds, int N,
    int* __restrict__ row_ptr, __half* __restrict__ table) {
  const long long t = (long long)blockIdx.x * BLOCK + threadIdx.x;

  if (table != nullptr) {
    if (t < (long long)N * 2) {   // 8 halves per thread
      const f32x4* src = (const f32x4*)embeds + t * 2;
      f32x4 a = src[0];
      f32x4 b = src[1];
      union { __half2 h[4]; u32x4 u; } o;
      o.h[0] = __floats2half2_rn(a[0], a[1]);
      o.h[1] = __floats2half2_rn(a[2], a[3]);
      o.h[2] = __floats2half2_rn(b[0], b[1]);
      o.h[3] = __floats2half2_rn(b[2], b[3]);
      *((u32x4*)table + t) = o.u;
    }
  }

  const long long e = t * 4;
  if (e < E) {
    int prev = (e == 0) ? -1 : row[e - 1];
    const int cnt = (E - e >= 4) ? 4 : (int)(E - e);
    int r[4];
    if (cnt == 4) {
      i32x4 r4 = *(const i32x4*)(row + e);
      r[0] = r4[0]; r[1] = r4[1]; r[2] = r4[2]; r[3] = r4[3];
    } else {
      for (int k = 0; k < cnt; ++k) r[k] = row[e + k];
    }
    for (int k = 0; k < cnt; ++k) {
      for (int n = prev + 1; n <= r[k]; ++n) row_ptr[n] = (int)e + k;
      prev = r[k];
    }
    if (e + cnt == E) {
      for (int n = prev + 1; n <= N; ++n) row_ptr[n] = E;
    }
  }
}

__global__ __launch_bounds__(BLOCK) void gcn_half_kernel(
    const int* __restrict__ col, const float* __restrict__ vals,
    const __half* __restrict__ table, const int* __restrict__ row_ptr,
    float* __restrict__ out, int N, int E) {
  __shared__ __align__(16) unsigned s_cv[SMEM_E * 2 + (SMEM_E * 2 / 64) * 4];

  const int t = threadIdx.x;
  const int n0 = blockIdx.x * NPB;
  const int nEnd = (n0 + NPB < N) ? n0 + NPB : N;
  const int g = t >> 2;                 // group = node
  const unsigned l = (unsigned)(t & 3);
  const unsigned s = l >> 1;            // edge parity this lane consumes
  const unsigned h16 = (l & 1) << 4;    // byte offset of this lane's 16B half
  const int node = n0 + g;
  const bool active = (node < nEnd);

  const int Wb = row_ptr[n0] & ~3;
  const int We = row_ptr[nEnd];
  const int beg = active ? row_ptr[node] : 0;
  const int end = active ? row_ptr[node + 1] : 0;
  const char* tb = (const char*)table;

  float acc[8] = {0.f, 0.f, 0.f, 0.f, 0.f, 0.f, 0.f, 0.f};

  for (int W0 = Wb; W0 < We; W0 += SMEM_E) {
    const int cnt  = (SMEM_E < We - W0) ? SMEM_E : (We - W0);
    const int cntP = (cnt + 7) & ~7;
    __syncthreads();
    // Cooperative coalesced staging: 4 edges/thread/pass, 3 passes.
    for (int i = t * 4; i < cntP; i += BLOCK * 4) {
      const int e = W0 + i;
      unsigned c[4], v[4];
      if (e + 3 < E) {
        i32x4 c4 = *(const i32x4*)(col + e);
        f32x4 v4 = *(const f32x4*)(vals + e);
        #pragma unroll
        for (int k = 0; k < 4; ++k) {
          c[k] = (unsigned)c4[k];
          v[k] = __float_as_uint(v4[k]);
        }
      } else {
        #pragma unroll
        for (int k = 0; k < 4; ++k) {
          const bool ok = (e + k < E);
          c[k] = ok ? (unsigned)col[e + k] : 0u;
          v[k] = ok ? __float_as_uint(vals[e + k]) : 0u;
        }
      }
      *(u32x4*)(s_cv + cvIdx((unsigned)i * 2))     = (u32x4){c[0], v[0], c[1], v[1]};
      *(u32x4*)(s_cv + cvIdx((unsigned)i * 2) + 4) = (u32x4){c[2], v[2], c[3], v[3]};
    }
    __syncthreads();

    const int gb = (beg > W0) ? beg : W0;
    const int ge = (end < W0 + cnt) ? end : (W0 + cnt);
    if (ge > gb) {
      const unsigned span = (unsigned)(ge - gb);
      const int e0 = W0 + ((gb - W0) & ~7);
      const int e1 = e0 + ((ge - e0 + 7) & ~7);   // <= W0 + cntP

      for (int e = e0; e < e1; e += 8) {
        const unsigned ci = cvIdx((unsigned)(e - W0) * 2);
        // Metadata via LDS broadcast (lgkmcnt): M[k] = {c2k,v2k,c2k+1,v2k+1}.
        u32x4 M0 = *(const u32x4*)(s_cv + ci);
        u32x4 M1 = *(const u32x4*)(s_cv + ci + 4);
        u32x4 M2 = *(const u32x4*)(s_cv + ci + 8);
        u32x4 M3 = *(const u32x4*)(s_cv + ci + 12);
        // 4 dwordx4 gathers: lane handles edge e+2k+s, half h (2 addr/edge).
        const unsigned c0 = M0[s << 1], w0b = M0[(s << 1) + 1];
        const unsigned c1 = M1[s << 1], w1b = M1[(s << 1) + 1];
        const unsigned c2 = M2[s << 1], w2b = M2[(s << 1) + 1];
        const unsigned c3 = M3[s << 1], w3b = M3[(s << 1) + 1];
        u32x4 G0 = *(const u32x4*)(tb + ((size_t)c0 << 5) + h16);
        u32x4 G1 = *(const u32x4*)(tb + ((size_t)c1 << 5) + h16);
        u32x4 G2 = *(const u32x4*)(tb + ((size_t)c2 << 5) + h16);
        u32x4 G3 = *(const u32x4*)(tb + ((size_t)c3 << 5) + h16);
#define EDGE(k, GG, wb)                                                     \
        {                                                                   \
          const float w = ((unsigned)(e + 2 * k + (int)s - gb) < span)      \
                              ? __uint_as_float(wb) : 0.f;                  \
          const float2 f0 = h2f(GG[0]), f1 = h2f(GG[1]);                    \
          const float2 f2 = h2f(GG[2]), f3 = h2f(GG[3]);                    \
          acc[0] = fmaf(w, f0.x, acc[0]);                                   \
          acc[1] = fmaf(w, f0.y, acc[1]);                                   \
          acc[2] = fmaf(w, f1.x, acc[2]);                                   \
          acc[3] = fmaf(w, f1.y, acc[3]);                                   \
          acc[4] = fmaf(w, f2.x, acc[4]);                                   \
          acc[5] = fmaf(w, f2.y, acc[5]);                                   \
          acc[6] = fmaf(w, f3.x, acc[6]);                                   \
          acc[7] = fmaf(w, f3.y, acc[7]);                                   \
        }
        EDGE(0, G0, w0b)
        EDGE(1, G1, w1b)
        EDGE(2, G2, w2b)
        EDGE(3, G3, w3b)
#undef EDGE
      }
    }
  }

  // Combine the two edge-parities: lane l += lane l^2.
  #pragma unroll
  for (int j = 0; j < 8; ++j) acc[j] += __shfl_xor(acc[j], 2, 64);

  if (active && s == 0) {  // lanes 0,1 store their 8 features (32B each)
    float* p = out + (size_t)node * D + (l & 1) * 8;
    f32x4 lo = {acc[0], acc[1], acc[2], acc[3]};
    f32x4 hi = {acc[4], acc[5], acc[6], acc[7]};
    __builtin_nontemporal_store(lo, (f32x4*)p);
    __builtin_nontemporal_store(hi, (f32x4*)(p + 4));
  }
}

// Fallback (f32 gathers straight from embeds) if ws can't hold the table.
__global__ __launch_bounds__(BLOCK) void gcn_node_f32_kernel(
    const int* __restrict__ col, const float* __restrict__ vals,
    const f32x4* __restrict__ embeds4, const int* __restrict__ row_ptr,
    f32x4* __restrict__ out4, int N, int E) {
  const int t = blockIdx.x * BLOCK + threadIdx.x;
  const int node = t >> 2;
  const int q = t & 3;
  if (node >= N) return;
  const int beg = row_ptr[node];
  const int end = row_ptr[node + 1];
  f32x4 acc = {0.f, 0.f, 0.f, 0.f};
  for (int e = beg; e < end; ++e) {
    acc += vals[e] * embeds4[(long long)col[e] * 4 + q];
  }
  __builtin_nontemporal_store(acc, out4 + (long long)node * 4 + q);
}

extern "C" void kernel_launch(void* const* d_in, const int* in_sizes, int n_in,
                              void* d_out, int out_size, void* d_ws, size_t ws_size,
                              hipStream_t stream) {
  const int*   row    = (const int*)d_in[0];
  const int*   col    = (const int*)d_in[1];
  const float* vals   = (const float*)d_in[2];
  const float* embeds = (const float*)d_in[3];

  const int E = in_sizes[0];
  const int N = in_sizes[3] / D;

  const size_t rp_bytes  = ((size_t)(N + 1) * 4 + 511) & ~(size_t)511;
  const size_t tbl_bytes = (size_t)N * D * sizeof(__half);
  const bool use_half = (ws_size >= rp_bytes + tbl_bytes) && (E >= 8);

  int*    row_ptr = (int*)d_ws;
  __half* table   = use_half ? (__half*)((char*)d_ws + rp_bytes) : nullptr;

  {
    long long chunksB = ((long long)E + 3) / 4;
    long long chunksA = use_half ? (long long)N * 2 : 0;
    long long threads = chunksB > chunksA ? chunksB : chunksA;
    int grid = (int)((threads + BLOCK - 1) / BLOCK);
    prep_kernel<<<grid, BLOCK, 0, stream>>>(row, E, embeds, N, row_ptr, table);
  }
  if (use_half) {
    const int grid = (N + NPB - 1) / NPB;
    gcn_half_kernel<<<grid, BLOCK, 0, stream>>>(
        col, vals, table, row_ptr, (float*)d_out, N, E);
  } else {
    long long threads = (long long)N * 4;
    int grid = (int)((threads + BLOCK - 1) / BLOCK);
    gcn_node_f32_kernel<<<grid, BLOCK, 0, stream>>>(
        col, vals, (const f32x4*)embeds, row_ptr, (f32x4*)d_out, N, E);
  }
}